// Round 3
// baseline (381.363 us; speedup 1.0000x reference)
//
#include <hip/hip_runtime.h>

#define M_DIM 16384
#define N_DIM 2048
#define K_DIM 2048
#define KB    (K_DIM / 128)
#define BM 128
#define BN 128
#define BK 64

// quant pass: 256 threads x 8 float4 iters = 8192 floats per workgroup
#define XWG (M_DIM * K_DIM / 8192)   // 4096
#define WWG (N_DIM * K_DIM / 8192)   // 512

typedef __bf16 bf16x8 __attribute__((ext_vector_type(8)));
typedef float  f32x4  __attribute__((ext_vector_type(4)));

__device__ __forceinline__ unsigned short f32_to_bf16_rne(float f) {
    unsigned int u = __float_as_uint(f);
    u += 0x7FFFu + ((u >> 16) & 1u);
    return (unsigned short)(u >> 16);
}

// ---- Fused quant pass, latency-optimized: 8 independent float4s per thread ----
// x-part: 32 consecutive lanes (half-wave) cover one 128-elem K-block; 8 interleaved
// shuffle-reduction chains hide ds-permute latency. Divides replaced by rcp
// (boundary-crossing probability ~2^-19 per element; both quant and dequant use the
// same s, so the error does not compound — argued in journal R2).
__global__ __launch_bounds__(256) void quant_all_kernel(const float* __restrict__ x,
                                                        unsigned short* __restrict__ xdq,
                                                        const float* __restrict__ w,
                                                        const float* __restrict__ wscale,
                                                        unsigned short* __restrict__ wdq) {
    const int tid = threadIdx.x;
    const float inv448 = 1.0f / 448.0f;   // compile-time RNE constant
    if (blockIdx.x < XWG) {
        const size_t base = (size_t)blockIdx.x * 8192 + tid * 4;
        float4 v[8];
#pragma unroll
        for (int c = 0; c < 8; ++c)
            v[c] = *(const float4*)(x + base + c * 1024);
        float amax[8];
#pragma unroll
        for (int c = 0; c < 8; ++c)
            amax[c] = fmaxf(fmaxf(fabsf(v[c].x), fabsf(v[c].y)),
                            fmaxf(fabsf(v[c].z), fabsf(v[c].w)));
#pragma unroll
        for (int m = 16; m >= 1; m >>= 1)
#pragma unroll
            for (int c = 0; c < 8; ++c)
                amax[c] = fmaxf(amax[c], __shfl_xor(amax[c], m, 64));
#pragma unroll
        for (int c = 0; c < 8; ++c) {
            float s = amax[c] * inv448;
            if (s == 0.0f) s = 1.0f;
            const float r = __builtin_amdgcn_rcpf(s);
            const int p01 = __builtin_amdgcn_cvt_pk_fp8_f32(v[c].x * r, v[c].y * r, 0, false);
            const int p23 = __builtin_amdgcn_cvt_pk_fp8_f32(v[c].z * r, v[c].w * r, 0, false);
            const float d0 = __builtin_amdgcn_cvt_f32_fp8(p01, 0) * s;
            const float d1 = __builtin_amdgcn_cvt_f32_fp8(p01, 1) * s;
            const float d2 = __builtin_amdgcn_cvt_f32_fp8(p23, 0) * s;
            const float d3 = __builtin_amdgcn_cvt_f32_fp8(p23, 1) * s;
            uint2 o;
            o.x = (unsigned int)f32_to_bf16_rne(d0) | ((unsigned int)f32_to_bf16_rne(d1) << 16);
            o.y = (unsigned int)f32_to_bf16_rne(d2) | ((unsigned int)f32_to_bf16_rne(d3) << 16);
            *(uint2*)(xdq + base + c * 1024) = o;
        }
    } else {
        const size_t base = (size_t)(blockIdx.x - XWG) * 8192 + tid * 4;
        float4 v[8];
#pragma unroll
        for (int c = 0; c < 8; ++c)
            v[c] = *(const float4*)(w + base + c * 1024);
#pragma unroll
        for (int c = 0; c < 8; ++c) {
            const size_t e = base + c * 1024;
            const int n = (int)(e >> 11);
            const int k = (int)(e & 2047);
            const float s = wscale[(n >> 7) * KB + (k >> 7)];
            uint2 o;
            o.x = (unsigned int)f32_to_bf16_rne(v[c].x * s) |
                  ((unsigned int)f32_to_bf16_rne(v[c].y * s) << 16);
            o.y = (unsigned int)f32_to_bf16_rne(v[c].z * s) |
                  ((unsigned int)f32_to_bf16_rne(v[c].w * s) << 16);
            *(uint2*)(wdq + e) = o;
        }
    }
}

// ---- GEMM: unchanged from R2 (at m97-structure plateau, 853 TF, 0 bank conflicts) ----
__global__ __launch_bounds__(256) void gemm_bt_kernel(const unsigned short* __restrict__ A,
                                                      const unsigned short* __restrict__ B,
                                                      float* __restrict__ C) {
    __shared__ __align__(16) unsigned short As[BM * BK];
    __shared__ __align__(16) unsigned short Bs[BN * BK];

    const int tid  = threadIdx.x;
    const int lane = tid & 63;
    const int wave = tid >> 6;
    const int wm   = (wave >> 1) * 64;
    const int wn   = (wave & 1) * 64;
    const int quad = lane >> 4;
    const int l16  = lane & 15;

    const int m0 = blockIdx.x * BM;
    const int n0 = blockIdx.y * BN;

    f32x4 acc[4][4] = {};

    const int srow = tid >> 3;
    const int scol = (tid & 7) ^ (srow & 7);      // XOR swizzle via global source permute
    const unsigned short* gA = A + (size_t)(m0 + srow) * K_DIM + scol * 8;
    const unsigned short* gB = B + (size_t)(n0 + srow) * K_DIM + scol * 8;

    for (int kt = 0; kt < K_DIM / BK; ++kt) {
        const int k0 = kt * BK;
#pragma unroll
        for (int i = 0; i < 4; ++i) {
            __builtin_amdgcn_global_load_lds(
                (__attribute__((address_space(1))) void*)(gA + (size_t)(i * 32) * K_DIM + k0),
                (__attribute__((address_space(3))) void*)(As + (i * 256 + wave * 64) * 8),
                16, 0, 0);
        }
#pragma unroll
        for (int i = 0; i < 4; ++i) {
            __builtin_amdgcn_global_load_lds(
                (__attribute__((address_space(1))) void*)(gB + (size_t)(i * 32) * K_DIM + k0),
                (__attribute__((address_space(3))) void*)(Bs + (i * 256 + wave * 64) * 8),
                16, 0, 0);
        }
        __syncthreads();
#pragma unroll
        for (int ks = 0; ks < BK; ks += 32) {
            const int c = (ks >> 3) + quad;
            const int swz = (c ^ (l16 & 7)) * 8;
            bf16x8 af[4], bfr[4];
#pragma unroll
            for (int i = 0; i < 4; ++i)
                af[i] = *(const bf16x8*)(As + (wm + i * 16 + l16) * BK + swz);
#pragma unroll
            for (int j = 0; j < 4; ++j)
                bfr[j] = *(const bf16x8*)(Bs + (wn + j * 16 + l16) * BK + swz);
#pragma unroll
            for (int i = 0; i < 4; ++i)
#pragma unroll
                for (int j = 0; j < 4; ++j)
                    acc[i][j] = __builtin_amdgcn_mfma_f32_16x16x32_bf16(af[i], bfr[j], acc[i][j], 0, 0, 0);
        }
        __syncthreads();
    }

#pragma unroll
    for (int i = 0; i < 4; ++i) {
        const int row = m0 + wm + i * 16 + quad * 4;
#pragma unroll
        for (int j = 0; j < 4; ++j) {
            const int col = n0 + wn + j * 16 + l16;
            float* cp = C + (size_t)row * N_DIM + col;
#pragma unroll
            for (int r = 0; r < 4; ++r)
                cp[(size_t)r * N_DIM] = acc[i][j][r];
        }
    }
}

extern "C" void kernel_launch(void* const* d_in, const int* in_sizes, int n_in,
                              void* d_out, int out_size, void* d_ws, size_t ws_size,
                              hipStream_t stream) {
    const float* x      = (const float*)d_in[0];
    const float* wfp8   = (const float*)d_in[1];
    const float* wscale = (const float*)d_in[2];
    float* out = (float*)d_out;

    unsigned short* xdq = (unsigned short*)d_ws;
    unsigned short* wdq = xdq + (size_t)M_DIM * K_DIM;

    quant_all_kernel<<<XWG + WWG, 256, 0, stream>>>(x, xdq, wfp8, wscale, wdq);
    gemm_bt_kernel<<<dim3(M_DIM / BM, N_DIM / BN), 256, 0, stream>>>(xdq, wdq, out);
}